// Round 1
// baseline (391.605 us; speedup 1.0000x reference)
//
#include <hip/hip_runtime.h>
#include <hip/hip_bf16.h>

#define NNODE 1024
#define DIM 128
#define HEADS 8
#define DK 16
#define EDIM 16
#define BN 8               // target nodes per attn block
#define MR 16              // source rows per chunk
#define NCH 8              // chunks per block -> 128 source rows per block
#define KV_ROW 160         // k/v LDS row stride dwords = 8 h * 20
#define H_STRIDE 20        // 20h mod 32 distinct for h=0..7 -> conflict-free reads
#define EF_ROW 20          // ef m-stride (dwords)
#define EF_NSTR 324        // ef n-stride = 16*20+4: 324 mod 32 = 4 -> same skew algebra as 644
#define MK_STR 17
#define LOG2E 1.44269504f

// smem arena (floats): ef [0,2592) | kv [2592,7712) | mk ints [7712,7848)
// reduction scratch overlays [0,8448) after compute loop.
#define SMEM_F 8448
#define KV_OFF 2592
#define MK_OFF 7712

// ---------------- Kernel 1: LayerNorm + QKV projection ----------------
__global__ __launch_bounds__(384)
void ln_qkv_kernel(const float* __restrict__ x,
                   const float* __restrict__ Wq, const float* __restrict__ bq,
                   const float* __restrict__ Wk, const float* __restrict__ bk,
                   const float* __restrict__ Wv, const float* __restrict__ bv,
                   const float* __restrict__ gamma, const float* __restrict__ beta,
                   float* __restrict__ qg, float* __restrict__ kg, float* __restrict__ vg) {
    const int n = blockIdx.x;
    const int t = threadIdx.x;
    __shared__ float hrow[DIM];
    __shared__ float part[4];

    float xv = 0.f;
    if (t < 128) {
        xv = x[n * DIM + t];
        float v = xv;
        #pragma unroll
        for (int off = 32; off >= 1; off >>= 1) v += __shfl_xor(v, off);
        if ((t & 63) == 0) part[t >> 6] = v;
    }
    __syncthreads();
    const float mu = (part[0] + part[1]) * (1.0f / DIM);
    const float dx = xv - mu;
    if (t < 128) {
        float v = dx * dx;
        #pragma unroll
        for (int off = 32; off >= 1; off >>= 1) v += __shfl_xor(v, off);
        if ((t & 63) == 0) part[2 + (t >> 6)] = v;
    }
    __syncthreads();
    if (t < 128) {
        const float var = (part[2] + part[3]) * (1.0f / DIM);
        hrow[t] = dx * rsqrtf(var + 1e-5f) * gamma[t] + beta[t];
    }
    __syncthreads();

    const int which = t >> 7;          // 0,1,2 -> q,k,v (wave-uniform)
    const int col = t & 127;
    const float* W = (which == 0) ? Wq : (which == 1) ? Wk : Wv;
    const float* b = (which == 0) ? bq : (which == 1) ? bk : bv;
    float* o       = (which == 0) ? qg : (which == 1) ? kg : vg;
    float a0 = b[col], a1 = 0.f;       // dual accumulators: break 128-deep dep chain
    #pragma unroll 8
    for (int i = 0; i < DIM; i += 2) {
        a0 = fmaf(hrow[i],     W[i * DIM + col],       a0);
        a1 = fmaf(hrow[i + 1], W[(i + 1) * DIM + col], a1);
    }
    o[n * DIM + col] = a0 + a1;
}

// ---------------- Kernel 2: chunked attention partial, atomics out ----------------
// grid = (1024/BN) * (1024/(MR*NCH)) = 128*8 = 1024 blocks; 256 threads.
// Each block owns 8 target nodes and LOOPS over 8 chunks of 16 source rows,
// accumulating in registers -> 4x fewer global atomics than one-shot, and
// LDS shrinks to ~31.4 KB (arena 33.8 KB incl. reduce overlay) -> 4 blocks/CU.
// Thread map unchanged: s = t>>5 (m sub-slot), np = (t>>3)&3, h = t&7;
// thread handles n = np and np+4 (k/v LDS reads amortized over the n-pair).
// ALL register-array indices remain compile-time constants.
__global__ __launch_bounds__(256, 4)
void attn_kernel(const float* __restrict__ qg, const float* __restrict__ kg,
                 const float* __restrict__ vg, const float* __restrict__ ef,
                 const int* __restrict__ mask,
                 const float* __restrict__ Wae, const float* __restrict__ bae,
                 float* __restrict__ acc) {
    const int t = threadIdx.x;
    const int s  = t >> 5;        // 0..7 m sub-slot
    const int np = (t >> 3) & 3;  // n-pair id
    const int h  = t & 7;         // head
    const int wid = t >> 6, lane = t & 63;
    const int bx = blockIdx.x;
    const int n0  = (bx >> 3) * BN;
    const int mb0 = (bx & 7) * (MR * NCH);   // m-group: 128 consecutive source rows

    __shared__ float smem[SMEM_F];           // 33792 B arena
    float* ef_lds = smem;                    // [BN][EF_NSTR]
    float* k_lds  = smem + KV_OFF;           // [MR][KV_ROW]
    float* v_lds  = smem + KV_OFF + MR * KV_ROW;
    int*   mk_lds = (int*)(smem + MK_OFF);   // [BN][MK_STR]

    // --- per-thread constants (global, L2-hot); issued before loop, overlap stage ---
    float qreg[2][DK];
    #pragma unroll
    for (int hf = 0; hf < 2; ++hf) {
        const float* qp = qg + (size_t)(n0 + np + 4 * hf) * DIM + h * DK;
        #pragma unroll
        for (int d4 = 0; d4 < 4; ++d4) {
            const float4 qv = *(const float4*)(qp + d4 * 4);
            qreg[hf][d4 * 4 + 0] = qv.x; qreg[hf][d4 * 4 + 1] = qv.y;
            qreg[hf][d4 * 4 + 2] = qv.z; qreg[hf][d4 * 4 + 3] = qv.w;
        }
    }
    float waec[EDIM];
    #pragma unroll
    for (int e = 0; e < EDIM; ++e) waec[e] = Wae[e * HEADS + h] * LOG2E;
    const float baeh = bae[h] * LOG2E;

    float sl[2] = {0.f, 0.f};
    float accv[2][DK], accT[2][EDIM];
    #pragma unroll
    for (int hf = 0; hf < 2; ++hf) {
        #pragma unroll
        for (int d = 0; d < DK; ++d) accv[hf][d] = 0.f;
        #pragma unroll
        for (int e = 0; e < EDIM; ++e) accT[hf][e] = 0.f;
    }

    #pragma unroll 1
    for (int c = 0; c < NCH; ++c) {
        const int mb = mb0 + c * MR;
        if (c) __syncthreads();              // prev chunk's readers done

        // --- ef stage: 512 float4 chunks, 2 per thread, skewed layout ---
        #pragma unroll
        for (int r = 0; r < 2; ++r) {
            const int idx = t + 256 * r;     // 0..511
            const int nn = idx >> 6;         // 0..7
            const int mm = (idx >> 2) & 15;
            const int q4 = idx & 3;
            const float4 ev = *(const float4*)(ef + ((size_t)(n0 + nn) * NNODE + mb + mm) * EDIM + q4 * 4);
            *(float4*)&ef_lds[nn * EF_NSTR + mm * EF_ROW + q4 * 4] = ev;
        }
        // --- k/v stage into padded [mm][h][20] layout ---
        #pragma unroll
        for (int r = 0; r < 2; ++r) {
            const int idx = t + 256 * r;     // 0..511 16B-chunks
            const int mm = idx >> 5, c4 = idx & 31;
            const int hh = c4 >> 2, d4 = c4 & 3;
            const float4 kq = *(const float4*)(kg + (size_t)(mb + mm) * DIM + c4 * 4);
            const float4 vq = *(const float4*)(vg + (size_t)(mb + mm) * DIM + c4 * 4);
            *(float4*)&k_lds[mm * KV_ROW + hh * H_STRIDE + d4 * 4] = kq;
            *(float4*)&v_lds[mm * KV_ROW + hh * H_STRIDE + d4 * 4] = vq;
        }
        // --- mask stage: 128 ints ---
        if (t < BN * MR) {
            const int nn = t >> 4, mm = t & 15;
            mk_lds[nn * MK_STR + mm] = mask[(size_t)(n0 + nn) * NNODE + (mb + mm)];
        }
        __syncthreads();

        // --- compute: 2 m per thread, n-pair per m; all indices static ---
        #pragma unroll
        for (int j = 0; j < 2; ++j) {
            const int m = j * 8 + s;
            float kk[DK], vv[DK];
            const float* kp = &k_lds[m * KV_ROW + h * H_STRIDE];
            const float* vp = &v_lds[m * KV_ROW + h * H_STRIDE];
            #pragma unroll
            for (int d4 = 0; d4 < 4; ++d4) {
                const float4 k4 = *(const float4*)(kp + d4 * 4);
                kk[d4 * 4 + 0] = k4.x; kk[d4 * 4 + 1] = k4.y;
                kk[d4 * 4 + 2] = k4.z; kk[d4 * 4 + 3] = k4.w;
                const float4 v4 = *(const float4*)(vp + d4 * 4);
                vv[d4 * 4 + 0] = v4.x; vv[d4 * 4 + 1] = v4.y;
                vv[d4 * 4 + 2] = v4.z; vv[d4 * 4 + 3] = v4.w;
            }
            #pragma unroll
            for (int hf = 0; hf < 2; ++hf) {
                const int n = np + 4 * hf;
                const float* ep = &ef_lds[n * EF_NSTR + m * EF_ROW];
                float efv[EDIM];
                #pragma unroll
                for (int e4 = 0; e4 < 4; ++e4) {       // STATIC e4 (skew handles banks)
                    const float4 ev = *(const float4*)(ep + e4 * 4);
                    efv[e4 * 4 + 0] = ev.x; efv[e4 * 4 + 1] = ev.y;
                    efv[e4 * 4 + 2] = ev.z; efv[e4 * 4 + 3] = ev.w;
                }
                float bias = baeh, dot = 0.f;
                #pragma unroll
                for (int e = 0; e < EDIM; ++e) bias = fmaf(efv[e], waec[e], bias);
                #pragma unroll
                for (int d = 0; d < DK; ++d) dot = fmaf(qreg[hf][d], kk[d], dot);
                const float lg = fmaf(dot, 0.25f * LOG2E, bias);
                const float p = mk_lds[n * MK_STR + m] ? __builtin_amdgcn_exp2f(lg) : 0.f;
                sl[hf] += p;
                #pragma unroll
                for (int d = 0; d < DK; ++d) accv[hf][d] = fmaf(p, vv[d], accv[hf][d]);
                #pragma unroll
                for (int e = 0; e < EDIM; ++e) accT[hf][e] = fmaf(p, efv[e], accT[hf][e]);
            }
        }
    }

    // --- reduce s-pairs within wave (lane ^ 32) ---
    #pragma unroll
    for (int hf = 0; hf < 2; ++hf) {
        sl[hf] += __shfl_xor(sl[hf], 32);
        #pragma unroll
        for (int d = 0; d < DK; ++d) accv[hf][d] += __shfl_xor(accv[hf][d], 32);
        #pragma unroll
        for (int e = 0; e < EDIM; ++e) accT[hf][e] += __shfl_xor(accT[hf][e], 32);
    }
    __syncthreads();                 // all LDS reads done -> overlay reduction scratch
    float* red = smem;               // [w4][np4][h8][hf2][33] = 8448 f32 (== arena)
    if (lane < 32) {
        float* rp = &red[((wid * 4 + np) * 8 + h) * 66];
        #pragma unroll
        for (int hf = 0; hf < 2; ++hf) {
            rp[hf * 33 + 0] = sl[hf];
            #pragma unroll
            for (int d = 0; d < DK; ++d) rp[hf * 33 + 1 + d] = accv[hf][d];
            #pragma unroll
            for (int e = 0; e < EDIM; ++e) rp[hf * 33 + 17 + e] = accT[hf][e];
        }
    }
    __syncthreads();
    // --- combine 4 wave copies, one atomicAdd per value (2112 per block) ---
    for (int v = t; v < BN * HEADS * 33; v += 256) {
        const int n = v / 264;
        const int rem = v - n * 264;
        const int hh = rem / 33;
        const int idx = rem - hh * 33;
        const int nnp = n & 3, hf = n >> 2;
        float sum = 0.f;
        #pragma unroll
        for (int w = 0; w < 4; ++w)
            sum += red[((w * 4 + nnp) * 8 + hh) * 66 + hf * 33 + idx];
        atomicAdd(&acc[((size_t)(n0 + n) * HEADS + hh) * 33 + idx], sum);
    }
}

// ---------------- Kernel 3: epilogue (Wve, normalize, Wo, residual) ----------------
__global__ __launch_bounds__(128)
void final_kernel(const float* __restrict__ acc,
                  const float* __restrict__ Wve, const float* __restrict__ bve,
                  const float* __restrict__ x,
                  const float* __restrict__ Wo, const float* __restrict__ bo,
                  float* __restrict__ out) {
    const int n = blockIdx.x, t = threadIdx.x;
    __shared__ float ab[HEADS * 33];
    __shared__ float orow[DIM];
    for (int u = t; u < HEADS * 33; u += 128) ab[u] = acc[(size_t)n * HEADS * 33 + u];
    __syncthreads();
    const int col = t, hh = col >> 4, dd = col & 15;
    const float slv = ab[hh * 33];
    float acc2 = 0.f;
    #pragma unroll
    for (int e = 0; e < EDIM; ++e) acc2 = fmaf(ab[hh * 33 + 17 + e], Wve[e * DIM + col], acc2);
    orow[col] = (ab[hh * 33 + 1 + dd] + acc2) / slv + bve[col];
    __syncthreads();
    float o0 = bo[col] + x[(size_t)n * DIM + col], o1 = 0.f;
    #pragma unroll 8
    for (int i = 0; i < DIM; i += 2) {
        o0 = fmaf(orow[i],     Wo[i * DIM + col],       o0);
        o1 = fmaf(orow[i + 1], Wo[(i + 1) * DIM + col], o1);
    }
    out[(size_t)n * DIM + col] = o0 + o1;
}

extern "C" void kernel_launch(void* const* d_in, const int* in_sizes, int n_in,
                              void* d_out, int out_size, void* d_ws, size_t ws_size,
                              hipStream_t stream) {
    const float* x     = (const float*)d_in[0];
    const float* ef    = (const float*)d_in[1];
    const int*   mask  = (const int*)d_in[2];
    const float* Wq    = (const float*)d_in[3];
    const float* bq    = (const float*)d_in[4];
    const float* Wk    = (const float*)d_in[5];
    const float* bk    = (const float*)d_in[6];
    const float* Wv    = (const float*)d_in[7];
    const float* bv    = (const float*)d_in[8];
    const float* Wae   = (const float*)d_in[9];
    const float* bae   = (const float*)d_in[10];
    const float* Wve   = (const float*)d_in[11];
    const float* bve   = (const float*)d_in[12];
    const float* Wo    = (const float*)d_in[13];
    const float* bo    = (const float*)d_in[14];
    const float* gamma = (const float*)d_in[15];
    const float* beta  = (const float*)d_in[16];

    float* ws = (float*)d_ws;
    float* accb = ws;                                   // 1024*8*33 = 270336 f32
    float* qg   = ws + 270336;
    float* kg   = qg + (size_t)NNODE * DIM;
    float* vg   = kg + (size_t)NNODE * DIM;

    hipMemsetAsync(accb, 0, (size_t)NNODE * HEADS * 33 * sizeof(float), stream);
    ln_qkv_kernel<<<NNODE, 384, 0, stream>>>(x, Wq, bq, Wk, bk, Wv, bv, gamma, beta, qg, kg, vg);
    attn_kernel<<<(NNODE / BN) * (NNODE / (MR * NCH)), 256, 0, stream>>>(qg, kg, vg, ef, mask, Wae, bae, accb);
    final_kernel<<<NNODE, 128, 0, stream>>>(accb, Wve, bve, x, Wo, bo, (float*)d_out);
}

// Round 2
// 178.576 us; speedup vs baseline: 2.1929x; 2.1929x over previous
//
#include <hip/hip_runtime.h>
#include <hip/hip_bf16.h>

#define NNODE 1024
#define DIM 128
#define HEADS 8
#define DK 16
#define EDIM 16
#define BN 8               // target nodes per attn block
#define MR 16              // source rows per chunk
#define NCH 8              // chunks per block -> 128 source rows per block
#define NGRP 8             // m-group blocks per target row (1024/(MR*NCH))
#define KV_ROW 160         // k/v LDS row stride dwords = 8 h * 20
#define H_STRIDE 20        // 20h mod 32 distinct for h=0..7 -> conflict-free reads
#define EF_ROW 20          // ef m-stride (dwords)
#define EF_NSTR 324        // ef n-stride = 16*20+4: 324 mod 32 = 4 -> same skew algebra as 644
#define MK_STR 17
#define LOG2E 1.44269504f

// smem arena (floats): ef [0,2592) | kv [2592,7712) | mk ints [7712,7848)
// reduction scratch overlays [0,8448) after compute loop.
#define SMEM_F 8448
#define KV_OFF 2592
#define MK_OFF 7712

// ---------------- Kernel 1: LayerNorm + QKV projection ----------------
__global__ __launch_bounds__(384)
void ln_qkv_kernel(const float* __restrict__ x,
                   const float* __restrict__ Wq, const float* __restrict__ bq,
                   const float* __restrict__ Wk, const float* __restrict__ bk,
                   const float* __restrict__ Wv, const float* __restrict__ bv,
                   const float* __restrict__ gamma, const float* __restrict__ beta,
                   float* __restrict__ qg, float* __restrict__ kg, float* __restrict__ vg) {
    const int n = blockIdx.x;
    const int t = threadIdx.x;
    __shared__ float hrow[DIM];
    __shared__ float part[4];

    float xv = 0.f;
    if (t < 128) {
        xv = x[n * DIM + t];
        float v = xv;
        #pragma unroll
        for (int off = 32; off >= 1; off >>= 1) v += __shfl_xor(v, off);
        if ((t & 63) == 0) part[t >> 6] = v;
    }
    __syncthreads();
    const float mu = (part[0] + part[1]) * (1.0f / DIM);
    const float dx = xv - mu;
    if (t < 128) {
        float v = dx * dx;
        #pragma unroll
        for (int off = 32; off >= 1; off >>= 1) v += __shfl_xor(v, off);
        if ((t & 63) == 0) part[2 + (t >> 6)] = v;
    }
    __syncthreads();
    if (t < 128) {
        const float var = (part[2] + part[3]) * (1.0f / DIM);
        hrow[t] = dx * rsqrtf(var + 1e-5f) * gamma[t] + beta[t];
    }
    __syncthreads();

    const int which = t >> 7;          // 0,1,2 -> q,k,v (wave-uniform)
    const int col = t & 127;
    const float* W = (which == 0) ? Wq : (which == 1) ? Wk : Wv;
    const float* b = (which == 0) ? bq : (which == 1) ? bk : bv;
    float* o       = (which == 0) ? qg : (which == 1) ? kg : vg;
    float a0 = b[col], a1 = 0.f;       // dual accumulators: break 128-deep dep chain
    #pragma unroll 8
    for (int i = 0; i < DIM; i += 2) {
        a0 = fmaf(hrow[i],     W[i * DIM + col],       a0);
        a1 = fmaf(hrow[i + 1], W[(i + 1) * DIM + col], a1);
    }
    o[n * DIM + col] = a0 + a1;
}

// ---------------- Kernel 2: chunked attention partial, per-group stores ----------------
// grid = (1024/BN) * NGRP = 128*8 = 1024 blocks; 256 threads.
// Each block owns 8 target nodes and LOOPS over 8 chunks of 16 source rows,
// accumulating in registers. Partials go to a PRIVATE group slot (plain stores,
// no atomics, no memset); final_kernel sums the 8 group partials.
// launch_bounds: (256,2) — round-1 lesson: (256,4) made the backend allocate for
// 8 waves/EU (64 VGPRs) and spill ~50 regs/thread to scratch (+850 MB HBM, 4x slower).
// Round 0 proved this inner loop fits in 116 VGPRs under (256,2); LDS 33.8 KB
// then allows 4 blocks/CU as long as VGPR <= 128.
// Thread map: s = t>>5 (m sub-slot), np = (t>>3)&3, h = t&7;
// thread handles n = np and np+4 (k/v LDS reads amortized over the n-pair).
// ALL register-array indices remain compile-time constants.
__global__ __launch_bounds__(256, 2)
void attn_kernel(const float* __restrict__ qg, const float* __restrict__ kg,
                 const float* __restrict__ vg, const float* __restrict__ ef,
                 const int* __restrict__ mask,
                 const float* __restrict__ Wae, const float* __restrict__ bae,
                 float* __restrict__ acc) {
    const int t = threadIdx.x;
    const int s  = t >> 5;        // 0..7 m sub-slot
    const int np = (t >> 3) & 3;  // n-pair id
    const int h  = t & 7;         // head
    const int wid = t >> 6, lane = t & 63;
    const int bx = blockIdx.x;
    const int n0  = (bx >> 3) * BN;
    const int grp = bx & 7;
    const int mb0 = grp * (MR * NCH);        // m-group: 128 consecutive source rows

    __shared__ float smem[SMEM_F];           // 33792 B arena
    float* ef_lds = smem;                    // [BN][EF_NSTR]
    float* k_lds  = smem + KV_OFF;           // [MR][KV_ROW]
    float* v_lds  = smem + KV_OFF + MR * KV_ROW;
    int*   mk_lds = (int*)(smem + MK_OFF);   // [BN][MK_STR]

    // --- per-thread constants (global, L2-hot); issued before loop, overlap stage ---
    float qreg[2][DK];
    #pragma unroll
    for (int hf = 0; hf < 2; ++hf) {
        const float* qp = qg + (size_t)(n0 + np + 4 * hf) * DIM + h * DK;
        #pragma unroll
        for (int d4 = 0; d4 < 4; ++d4) {
            const float4 qv = *(const float4*)(qp + d4 * 4);
            qreg[hf][d4 * 4 + 0] = qv.x; qreg[hf][d4 * 4 + 1] = qv.y;
            qreg[hf][d4 * 4 + 2] = qv.z; qreg[hf][d4 * 4 + 3] = qv.w;
        }
    }
    float waec[EDIM];
    #pragma unroll
    for (int e = 0; e < EDIM; ++e) waec[e] = Wae[e * HEADS + h] * LOG2E;
    const float baeh = bae[h] * LOG2E;

    float sl[2] = {0.f, 0.f};
    float accv[2][DK], accT[2][EDIM];
    #pragma unroll
    for (int hf = 0; hf < 2; ++hf) {
        #pragma unroll
        for (int d = 0; d < DK; ++d) accv[hf][d] = 0.f;
        #pragma unroll
        for (int e = 0; e < EDIM; ++e) accT[hf][e] = 0.f;
    }

    #pragma unroll 1
    for (int c = 0; c < NCH; ++c) {
        const int mb = mb0 + c * MR;
        if (c) __syncthreads();              // prev chunk's readers done

        // --- ef stage: 512 float4 chunks, 2 per thread, skewed layout ---
        #pragma unroll
        for (int r = 0; r < 2; ++r) {
            const int idx = t + 256 * r;     // 0..511
            const int nn = idx >> 6;         // 0..7
            const int mm = (idx >> 2) & 15;
            const int q4 = idx & 3;
            const float4 ev = *(const float4*)(ef + ((size_t)(n0 + nn) * NNODE + mb + mm) * EDIM + q4 * 4);
            *(float4*)&ef_lds[nn * EF_NSTR + mm * EF_ROW + q4 * 4] = ev;
        }
        // --- k/v stage into padded [mm][h][20] layout ---
        #pragma unroll
        for (int r = 0; r < 2; ++r) {
            const int idx = t + 256 * r;     // 0..511 16B-chunks
            const int mm = idx >> 5, c4 = idx & 31;
            const int hh = c4 >> 2, d4 = c4 & 3;
            const float4 kq = *(const float4*)(kg + (size_t)(mb + mm) * DIM + c4 * 4);
            const float4 vq = *(const float4*)(vg + (size_t)(mb + mm) * DIM + c4 * 4);
            *(float4*)&k_lds[mm * KV_ROW + hh * H_STRIDE + d4 * 4] = kq;
            *(float4*)&v_lds[mm * KV_ROW + hh * H_STRIDE + d4 * 4] = vq;
        }
        // --- mask stage: 128 ints ---
        if (t < BN * MR) {
            const int nn = t >> 4, mm = t & 15;
            mk_lds[nn * MK_STR + mm] = mask[(size_t)(n0 + nn) * NNODE + (mb + mm)];
        }
        __syncthreads();

        // --- compute: 2 m per thread, n-pair per m; all indices static ---
        #pragma unroll
        for (int j = 0; j < 2; ++j) {
            const int m = j * 8 + s;
            float kk[DK], vv[DK];
            const float* kp = &k_lds[m * KV_ROW + h * H_STRIDE];
            const float* vp = &v_lds[m * KV_ROW + h * H_STRIDE];
            #pragma unroll
            for (int d4 = 0; d4 < 4; ++d4) {
                const float4 k4 = *(const float4*)(kp + d4 * 4);
                kk[d4 * 4 + 0] = k4.x; kk[d4 * 4 + 1] = k4.y;
                kk[d4 * 4 + 2] = k4.z; kk[d4 * 4 + 3] = k4.w;
                const float4 v4 = *(const float4*)(vp + d4 * 4);
                vv[d4 * 4 + 0] = v4.x; vv[d4 * 4 + 1] = v4.y;
                vv[d4 * 4 + 2] = v4.z; vv[d4 * 4 + 3] = v4.w;
            }
            #pragma unroll
            for (int hf = 0; hf < 2; ++hf) {
                const int n = np + 4 * hf;
                const float* ep = &ef_lds[n * EF_NSTR + m * EF_ROW];
                float efv[EDIM];
                #pragma unroll
                for (int e4 = 0; e4 < 4; ++e4) {       // STATIC e4 (skew handles banks)
                    const float4 ev = *(const float4*)(ep + e4 * 4);
                    efv[e4 * 4 + 0] = ev.x; efv[e4 * 4 + 1] = ev.y;
                    efv[e4 * 4 + 2] = ev.z; efv[e4 * 4 + 3] = ev.w;
                }
                float bias = baeh, dot = 0.f;
                #pragma unroll
                for (int e = 0; e < EDIM; ++e) bias = fmaf(efv[e], waec[e], bias);
                #pragma unroll
                for (int d = 0; d < DK; ++d) dot = fmaf(qreg[hf][d], kk[d], dot);
                const float lg = fmaf(dot, 0.25f * LOG2E, bias);
                const float p = mk_lds[n * MK_STR + m] ? __builtin_amdgcn_exp2f(lg) : 0.f;
                sl[hf] += p;
                #pragma unroll
                for (int d = 0; d < DK; ++d) accv[hf][d] = fmaf(p, vv[d], accv[hf][d]);
                #pragma unroll
                for (int e = 0; e < EDIM; ++e) accT[hf][e] = fmaf(p, efv[e], accT[hf][e]);
            }
        }
    }

    // --- reduce s-pairs within wave (lane ^ 32) ---
    #pragma unroll
    for (int hf = 0; hf < 2; ++hf) {
        sl[hf] += __shfl_xor(sl[hf], 32);
        #pragma unroll
        for (int d = 0; d < DK; ++d) accv[hf][d] += __shfl_xor(accv[hf][d], 32);
        #pragma unroll
        for (int e = 0; e < EDIM; ++e) accT[hf][e] += __shfl_xor(accT[hf][e], 32);
    }
    __syncthreads();                 // all LDS reads done -> overlay reduction scratch
    float* red = smem;               // [w4][np4][h8][hf2][33] = 8448 f32 (== arena)
    if (lane < 32) {
        float* rp = &red[((wid * 4 + np) * 8 + h) * 66];
        #pragma unroll
        for (int hf = 0; hf < 2; ++hf) {
            rp[hf * 33 + 0] = sl[hf];
            #pragma unroll
            for (int d = 0; d < DK; ++d) rp[hf * 33 + 1 + d] = accv[hf][d];
            #pragma unroll
            for (int e = 0; e < EDIM; ++e) rp[hf * 33 + 17 + e] = accT[hf][e];
        }
    }
    __syncthreads();
    // --- combine 4 wave copies, plain store to this block's group slot ---
    // acc layout: [n][grp][264]; each (n,grp) written by exactly one block.
    for (int v = t; v < BN * HEADS * 33; v += 256) {   // 2112 values
        const int n = v / 264;
        const int rem = v - n * 264;
        const int hh = rem / 33;
        const int idx = rem - hh * 33;
        const int nnp = n & 3, hf = n >> 2;
        float sum = 0.f;
        #pragma unroll
        for (int w = 0; w < 4; ++w)
            sum += red[((w * 4 + nnp) * 8 + hh) * 66 + hf * 33 + idx];
        acc[((size_t)(n0 + n) * NGRP + grp) * 264 + rem] = sum;
    }
}

// ---------------- Kernel 3: epilogue (sum groups, Wve, normalize, Wo, residual) ----------------
__global__ __launch_bounds__(128)
void final_kernel(const float* __restrict__ acc,
                  const float* __restrict__ Wve, const float* __restrict__ bve,
                  const float* __restrict__ x,
                  const float* __restrict__ Wo, const float* __restrict__ bo,
                  float* __restrict__ out) {
    const int n = blockIdx.x, t = threadIdx.x;
    __shared__ float ab[HEADS * 33];
    __shared__ float orow[DIM];
    const float* ap = acc + (size_t)n * NGRP * 264;
    for (int u = t; u < HEADS * 33; u += 128) {
        float sv = 0.f;
        #pragma unroll
        for (int g = 0; g < NGRP; ++g) sv += ap[g * 264 + u];
        ab[u] = sv;
    }
    __syncthreads();
    const int col = t, hh = col >> 4, dd = col & 15;
    const float slv = ab[hh * 33];
    float acc2 = 0.f;
    #pragma unroll
    for (int e = 0; e < EDIM; ++e) acc2 = fmaf(ab[hh * 33 + 17 + e], Wve[e * DIM + col], acc2);
    orow[col] = (ab[hh * 33 + 1 + dd] + acc2) / slv + bve[col];
    __syncthreads();
    float o0 = bo[col] + x[(size_t)n * DIM + col], o1 = 0.f;
    #pragma unroll 8
    for (int i = 0; i < DIM; i += 2) {
        o0 = fmaf(orow[i],     Wo[i * DIM + col],       o0);
        o1 = fmaf(orow[i + 1], Wo[(i + 1) * DIM + col], o1);
    }
    out[(size_t)n * DIM + col] = o0 + o1;
}

extern "C" void kernel_launch(void* const* d_in, const int* in_sizes, int n_in,
                              void* d_out, int out_size, void* d_ws, size_t ws_size,
                              hipStream_t stream) {
    const float* x     = (const float*)d_in[0];
    const float* ef    = (const float*)d_in[1];
    const int*   mask  = (const int*)d_in[2];
    const float* Wq    = (const float*)d_in[3];
    const float* bq    = (const float*)d_in[4];
    const float* Wk    = (const float*)d_in[5];
    const float* bk    = (const float*)d_in[6];
    const float* Wv    = (const float*)d_in[7];
    const float* bv    = (const float*)d_in[8];
    const float* Wae   = (const float*)d_in[9];
    const float* bae   = (const float*)d_in[10];
    const float* Wve   = (const float*)d_in[11];
    const float* bve   = (const float*)d_in[12];
    const float* Wo    = (const float*)d_in[13];
    const float* bo    = (const float*)d_in[14];
    const float* gamma = (const float*)d_in[15];
    const float* beta  = (const float*)d_in[16];

    float* ws = (float*)d_ws;
    float* accb = ws;                                   // 1024*8*264 = 2162688 f32
    float* qg   = ws + (size_t)NNODE * NGRP * 264;
    float* kg   = qg + (size_t)NNODE * DIM;
    float* vg   = kg + (size_t)NNODE * DIM;

    ln_qkv_kernel<<<NNODE, 384, 0, stream>>>(x, Wq, bq, Wk, bk, Wv, bv, gamma, beta, qg, kg, vg);
    attn_kernel<<<(NNODE / BN) * NGRP, 256, 0, stream>>>(qg, kg, vg, ef, mask, Wae, bae, accb);
    final_kernel<<<NNODE, 128, 0, stream>>>(accb, Wve, bve, x, Wo, bo, (float*)d_out);
}